// Round 2
// baseline (117.801 us; speedup 1.0000x reference)
//
#include <hip/hip_runtime.h>
#include <math.h>

#define TWO_N 512
#define DM    256
#define NT    256

// ws layout: bsums [512] double @ 0
#define ACCD(acc, A, B) { float _d;                      \
    _d = (A).x - (B).x; acc += _d * _d;                  \
    _d = (A).y - (B).y; acc += _d * _d;                  \
    _d = (A).z - (B).z; acc += _d * _d;                  \
    _d = (A).w - (B).w; acc += _d * _d; }

// One block per row i, fully self-contained (no inter-block deps):
//   1. stage T and e_i into LDS
//   2. rank targets by counting (replaces global bitonic sort)
//   3. compute r_ij = ||e_i - e_j|| for this row directly from E (L2-hot)
//   4. scatter s~ into t-sorted order, prefix-sum, interval searches
//   5. write per-row sum to bsums[i] (no atomics)
__global__ __launch_bounds__(NT) void supcr_row_fused(
    const float* __restrict__ E, const float* __restrict__ T,
    double* __restrict__ bsums)
{
    const int i = blockIdx.x;
    const int t = threadIdx.x;

    __shared__ float4 ei4[DM / 4];   // e_i, broadcast-read
    __shared__ float  Tsh[TWO_N];    // raw targets
    __shared__ float  ts[TWO_N];     // sorted targets
    __shared__ float  P[TWO_N];      // s~ in sorted order -> inclusive prefix
    __shared__ double red[NT];
    __shared__ int    miS;           // sorted position of t_i

    const float4* __restrict__ E4 = reinterpret_cast<const float4*>(E);

    // ---- stage ----
    Tsh[t] = T[t]; Tsh[t + 256] = T[t + 256];
    if (t < DM / 4) ei4[t] = E4[(size_t)i * (DM / 4) + t];
    __syncthreads();

    const int ja = t, jb = t + 256;

    // ---- ranks of the two targets this thread owns (tie-break by index) ----
    const float ta = Tsh[ja], tb = Tsh[jb];
    int rka = 0, rkb = 0;
    const float4* Tsh4 = reinterpret_cast<const float4*>(Tsh);
    #pragma unroll 4
    for (int j4 = 0; j4 < TWO_N / 4; ++j4) {
        const float4 tv = Tsh4[j4];            // LDS broadcast (free)
        const int b0 = 4 * j4, b1 = b0 + 1, b2 = b0 + 2, b3 = b0 + 3;
        rka += (tv.x < ta) || (tv.x == ta && b0 < ja);
        rka += (tv.y < ta) || (tv.y == ta && b1 < ja);
        rka += (tv.z < ta) || (tv.z == ta && b2 < ja);
        rka += (tv.w < ta) || (tv.w == ta && b3 < ja);
        rkb += (tv.x < tb) || (tv.x == tb && b0 < jb);
        rkb += (tv.y < tb) || (tv.y == tb && b1 < jb);
        rkb += (tv.z < tb) || (tv.z == tb && b2 < jb);
        rkb += (tv.w < tb) || (tv.w == tb && b3 < jb);
    }

    // ---- distances r_ij for j = ja, jb (E rows streamed from L2) ----
    float d2a = 0.f, d2b = 0.f;
    #pragma unroll 8
    for (int k4 = 0; k4 < DM / 4; ++k4) {
        const float4 ev = ei4[k4];             // LDS broadcast
        const float4 av = E4[(size_t)ja * (DM / 4) + k4];
        const float4 bv = E4[(size_t)jb * (DM / 4) + k4];
        ACCD(d2a, ev, av); ACCD(d2b, ev, bv);
    }
    const float ra = sqrtf(d2a), rb = sqrtf(d2b);

    // ---- scatter into sorted order ----
    ts[rka] = ta;  P[rka] = (ja == i) ? 0.f : __expf(-ra);
    ts[rkb] = tb;  P[rkb] = (jb == i) ? 0.f : __expf(-rb);
    if (ja == i) miS = rka;
    if (jb == i) miS = rkb;
    __syncthreads();

    // ---- inclusive prefix sum (Hillis-Steele), 2 elems/thread ----
    for (int off = 1; off < TWO_N; off <<= 1) {
        const float v0 = (t >= off)       ? P[t - off]       : 0.f;
        const float v1 = (t + 256 >= off) ? P[t + 256 - off] : 0.f;
        __syncthreads();
        P[t]       += v0;
        P[t + 256] += v1;
        __syncthreads();
    }

    const float Stot = P[TWO_N - 1];
    const int   mi   = miS;
    const float ti   = Tsh[i];

    float local = 0.f;
    #pragma unroll
    for (int w = 0; w < 2; ++w) {
        const int k = t + w * 256;
        if (k == i) continue;
        const float theta = fabsf(ti - Tsh[k]);
        const float rik   = (w == 0) ? ra : rb;

        // left arm [0, mi]: d(m) = |ti - ts[m]| non-increasing.
        const int nl = mi + 1;
        int pos = 0;
        #pragma unroll
        for (int step = 512; step >= 1; step >>= 1) {
            const int np = pos + step;
            if (np <= nl && fabsf(ti - ts[np - 1]) >= theta) pos = np;
        }
        const int cl = nl - pos;                 // suffix with d < theta

        // right arm [mi, 511]: d non-decreasing; count leading d < theta.
        const int nr = TWO_N - mi;
        int pr = 0;
        #pragma unroll
        for (int step = 512; step >= 1; step >>= 1) {
            const int np = pr + step;
            if (np <= nr && fabsf(ti - ts[mi + np - 1]) < theta) pr = np;
        }
        const int cr = pr;

        // interval with d < theta: [mi-cl+1, mi+cr-1]
        float inner = 0.f;
        const int L  = mi - cl + 1;
        const int Rr = mi + cr - 1;
        if (Rr >= L) inner = P[Rr] - ((L > 0) ? P[L - 1] : 0.f);
        const float denom = Stot - inner;        // sum over {d >= theta, j != i}
        local += -rik - logf(denom);
    }

    red[t] = (double)local;
    __syncthreads();
    for (int off = NT / 2; off > 0; off >>= 1) {
        if (t < off) red[t] += red[t + off];
        __syncthreads();
    }
    if (t == 0) bsums[i] = red[0];
}

__global__ __launch_bounds__(TWO_N) void supcr_finalize(
    const double* __restrict__ bsums, float* __restrict__ out)
{
    __shared__ double red[TWO_N];
    const int t = threadIdx.x;
    red[t] = bsums[t];
    __syncthreads();
    for (int off = TWO_N / 2; off > 0; off >>= 1) {
        if (t < off) red[t] += red[t + off];
        __syncthreads();
    }
    if (t == 0)
        out[0] = (float)(-red[0] / (double)((long long)TWO_N * (TWO_N - 1)));
}

extern "C" void kernel_launch(void* const* d_in, const int* in_sizes, int n_in,
                              void* d_out, int out_size, void* d_ws, size_t ws_size,
                              hipStream_t stream) {
    (void)in_sizes; (void)n_in; (void)out_size; (void)ws_size;
    const float* E = (const float*)d_in[0];   // [512,256] fp32
    const float* T = (const float*)d_in[1];   // [512]     fp32
    float* out = (float*)d_out;
    double* bsums = (double*)d_ws;

    supcr_row_fused<<<TWO_N, NT, 0, stream>>>(E, T, bsums);
    supcr_finalize<<<1, TWO_N, 0, stream>>>(bsums, out);
}

// Round 4
// 93.663 us; speedup vs baseline: 1.2577x; 1.2577x over previous
//
#include <hip/hip_runtime.h>
#include <math.h>

#define TWO_N 512
#define DM    256
#define NT    256
#define NTR   512

// ws layout (bytes):
//   R0    : [512*512] float @ 0        (partial sq-dist, K 0..127)
//   R1    : [512*512] float @ 1 MB     (partial sq-dist, K 128..255)
//   tsort : [512] float     @ 2 MB
//   inv   : [512] int       @ 2 MB + 2048
//   bsums : [512] double    @ 2 MB + 4096
#define OFF_R1    (1u << 20)
#define OFF_TSORT (2u << 20)
#define OFF_INV   ((2u << 20) + 2048)
#define OFF_BSUM  ((2u << 20) + 4096)

#define ACC4(acc, A, B) { float _d;                      \
    _d = (A).x - (B).x; acc += _d * _d;                  \
    _d = (A).y - (B).y; acc += _d * _d;                  \
    _d = (A).z - (B).z; acc += _d * _d;                  \
    _d = (A).w - (B).w; acc += _d * _d; }

// Block 0: rank targets by counting (replaces 45-barrier bitonic sort).
// Blocks 1..512: 32x32 distance tiles, K-split in half (kh = parity).
//   Partial SQUARED sums only; sqrt happens in supcr_rows.
__global__ __launch_bounds__(NT) void supcr_dist_rank(
    const float* __restrict__ E, const float* __restrict__ T,
    float* __restrict__ R0, float* __restrict__ R1,
    float* __restrict__ tsort, int* __restrict__ inv)
{
    const int bid = blockIdx.x;
    const int t   = threadIdx.x;

    if (bid > 0) {
        const int tile = bid - 1;
        const int it = (tile >> 1) >> 4, jt = (tile >> 1) & 15, kh = tile & 1;
        __shared__ float4 As4[32 * 33];     // pad 33: conflict-free-ish
        __shared__ float4 Bs4[32 * 33];
        const float4* __restrict__ E4 = reinterpret_cast<const float4*>(E);

        for (int idx = t; idx < 32 * 32; idx += NT) {   // coalesced staging
            const int row = idx >> 5, c4 = idx & 31;
            As4[row * 33 + c4] = E4[(it * 32 + row) * 64 + kh * 32 + c4];
            Bs4[row * 33 + c4] = E4[(jt * 32 + row) * 64 + kh * 32 + c4];
        }
        __syncthreads();

        const int ty = t >> 4, tx = t & 15;
        float a00 = 0.f, a01 = 0.f, a10 = 0.f, a11 = 0.f;
        #pragma unroll 8
        for (int k4 = 0; k4 < 32; ++k4) {
            const float4 a0 = As4[ty * 33 + k4];
            const float4 a1 = As4[(ty + 16) * 33 + k4];
            const float4 b0 = Bs4[tx * 33 + k4];
            const float4 b1 = Bs4[(tx + 16) * 33 + k4];
            ACC4(a00, a0, b0); ACC4(a01, a0, b1);
            ACC4(a10, a1, b0); ACC4(a11, a1, b1);
        }
        float* __restrict__ Rp = kh ? R1 : R0;
        const int r0 = it * 32 + ty, r1 = r0 + 16;
        const int c0 = jt * 32 + tx, c1 = c0 + 16;
        Rp[r0 * TWO_N + c0] = a00;
        Rp[r0 * TWO_N + c1] = a01;
        Rp[r1 * TWO_N + c0] = a10;
        Rp[r1 * TWO_N + c1] = a11;
    } else {
        // rank by counting: stable total order (value, then index)
        __shared__ float Tsh[TWO_N];
        Tsh[t] = T[t]; Tsh[t + 256] = T[t + 256];
        __syncthreads();

        const int ja = t, jb = t + 256;
        const float ta = Tsh[ja], tb = Tsh[jb];
        int rka = 0, rkb = 0;
        const float4* Tsh4 = reinterpret_cast<const float4*>(Tsh);
        #pragma unroll 4
        for (int j4 = 0; j4 < TWO_N / 4; ++j4) {
            const float4 tv = Tsh4[j4];          // LDS broadcast
            const int b0 = 4 * j4, b1 = b0 + 1, b2 = b0 + 2, b3 = b0 + 3;
            rka += (tv.x < ta) || (tv.x == ta && b0 < ja);
            rka += (tv.y < ta) || (tv.y == ta && b1 < ja);
            rka += (tv.z < ta) || (tv.z == ta && b2 < ja);
            rka += (tv.w < ta) || (tv.w == ta && b3 < ja);
            rkb += (tv.x < tb) || (tv.x == tb && b0 < jb);
            rkb += (tv.y < tb) || (tv.y == tb && b1 < jb);
            rkb += (tv.z < tb) || (tv.z == tb && b2 < jb);
            rkb += (tv.w < tb) || (tv.w == tb && b3 < jb);
        }
        tsort[rka] = ta;  inv[ja] = rka;
        tsort[rkb] = tb;  inv[jb] = rkb;
    }
}

// One block per row i, 512 threads (one k each):
//   coalesced R0+R1 loads -> rik; LDS scatter via inv (no global gather);
//   shfl-based double-precision scan (2 barriers); interval searches;
//   shfl reduce. 4 barriers total.
__global__ __launch_bounds__(NTR) void supcr_rows(
    const float* __restrict__ T, const float* __restrict__ R0,
    const float* __restrict__ R1, const float* __restrict__ tsort,
    const int* __restrict__ inv, double* __restrict__ bsums)
{
    const int i = blockIdx.x;
    const int k = threadIdx.x;
    const int lane = k & 63, wid = k >> 6;

    __shared__ float  ts[TWO_N];     // sorted targets
    __shared__ float  Pe[TWO_N];     // s~ scattered into sorted order
    __shared__ double P[TWO_N];      // inclusive prefix sums (double)
    __shared__ double wsum[8];
    __shared__ double red8[8];

    const float ti  = T[i];
    const float tk  = T[k];
    const float d2  = R0[(size_t)i * TWO_N + k] + R1[(size_t)i * TWO_N + k];
    const float rik = sqrtf(d2);
    const float e   = (k == i) ? 0.f : __expf(-rik);

    ts[k] = tsort[k];
    Pe[inv[k]] = e;                  // scatter: sorted-order s~
    __syncthreads();

    // inclusive scan over sorted order, double precision, via wave shuffles
    double v = (double)Pe[k];
    #pragma unroll
    for (int off = 1; off < 64; off <<= 1) {
        const double u = __shfl_up(v, off, 64);
        if (lane >= off) v += u;
    }
    if (lane == 63) wsum[wid] = v;
    __syncthreads();
    double base = 0.0, tot = 0.0;
    #pragma unroll
    for (int w = 0; w < 8; ++w) {
        const double s = wsum[w];    // LDS broadcast
        tot += s;
        if (w < wid) base += s;
    }
    P[k] = v + base;
    const double Stot = tot;
    __syncthreads();

    const int mi = inv[i];           // same address all threads: cached

    double local = 0.0;
    if (k != i) {
        const float theta = fabsf(ti - tk);

        // left arm [0, mi]: d(m) = |ti - ts[m]| non-increasing;
        // count leading elements with d >= theta (monotone prefix).
        const int nl = mi + 1;
        int pos = 0;
        #pragma unroll
        for (int step = 512; step >= 1; step >>= 1) {
            const int np = pos + step;
            if (np <= nl && fabsf(ti - ts[np - 1]) >= theta) pos = np;
        }
        const int cl = nl - pos;                 // suffix with d < theta

        // right arm [mi, 511]: d non-decreasing; count leading d < theta.
        const int nr = TWO_N - mi;
        int pr = 0;
        #pragma unroll
        for (int step = 512; step >= 1; step >>= 1) {
            const int np = pr + step;
            if (np <= nr && fabsf(ti - ts[mi + np - 1]) < theta) pr = np;
        }
        const int cr = pr;

        // interval with d < theta: [mi-cl+1, mi+cr-1]
        double inner = 0.0;
        const int L  = mi - cl + 1;
        const int Rr = mi + cr - 1;
        if (Rr >= L) inner = P[Rr] - ((L > 0) ? P[L - 1] : 0.0);
        const float denom = (float)(Stot - inner);   // {d >= theta, j != i}
        local = (double)(-rik - logf(denom));
    }

    // block reduction: wave shfl, then 8 partials
    #pragma unroll
    for (int off = 32; off > 0; off >>= 1) local += __shfl_down(local, off, 64);
    if (lane == 0) red8[wid] = local;
    __syncthreads();
    if (k == 0) {
        double s = 0.0;
        #pragma unroll
        for (int w = 0; w < 8; ++w) s += red8[w];
        bsums[i] = s;
    }
}

__global__ __launch_bounds__(64) void supcr_finalize(
    const double* __restrict__ bsums, float* __restrict__ out)
{
    const int t = threadIdx.x;
    double s = 0.0;
    #pragma unroll
    for (int w = 0; w < 8; ++w) s += bsums[t + 64 * w];
    #pragma unroll
    for (int off = 32; off > 0; off >>= 1) s += __shfl_down(s, off, 64);
    if (t == 0)
        out[0] = (float)(-s / (double)((long long)TWO_N * (TWO_N - 1)));
}

extern "C" void kernel_launch(void* const* d_in, const int* in_sizes, int n_in,
                              void* d_out, int out_size, void* d_ws, size_t ws_size,
                              hipStream_t stream) {
    (void)in_sizes; (void)n_in; (void)out_size; (void)ws_size;
    const float* E = (const float*)d_in[0];   // [512,256] fp32
    const float* T = (const float*)d_in[1];   // [512]     fp32
    float* out = (float*)d_out;

    char* ws = (char*)d_ws;
    float*  R0     = (float*)(ws);
    float*  R1     = (float*)(ws + OFF_R1);
    float*  tsortp = (float*)(ws + OFF_TSORT);
    int*    invp   = (int*)(ws + OFF_INV);
    double* bsums  = (double*)(ws + OFF_BSUM);

    supcr_dist_rank<<<513, NT, 0, stream>>>(E, T, R0, R1, tsortp, invp);
    supcr_rows<<<TWO_N, NTR, 0, stream>>>(T, R0, R1, tsortp, invp, bsums);
    supcr_finalize<<<1, 64, 0, stream>>>(bsums, out);
}

// Round 5
// 93.517 us; speedup vs baseline: 1.2597x; 1.0016x over previous
//
#include <hip/hip_runtime.h>
#include <math.h>

#define TWO_N 512
#define DM    256
#define NT    256
#define NTR   512
#define KS    8                      // K-split factor (32 dims per partial)
#define RSTRIDE (TWO_N * TWO_N)      // floats per partial matrix (1 MB)

// ws layout (bytes):
//   R[8]  : 8 x [512*512] float @ 0      (8 MB partial squared distances)
//   tsort : [512] float @ 8 MB
//   inv   : [512] int   @ 8 MB + 2048
//   bsums : [512] double@ 8 MB + 4096
#define OFF_TSORT (8u << 20)
#define OFF_INV   ((8u << 20) + 2048)
#define OFF_BSUM  ((8u << 20) + 4096)

#define ACC4(acc, A, B) { float _d;                      \
    _d = (A).x - (B).x; acc += _d * _d;                  \
    _d = (A).y - (B).y; acc += _d * _d;                  \
    _d = (A).z - (B).z; acc += _d * _d;                  \
    _d = (A).w - (B).w; acc += _d * _d; }

// Blocks 0..511: 64x64 distance tiles, 4x4 register blocking per thread,
//   K-split 8 (32 dims each). Each ds_read_b128 feeds 4 ACC4s -> LDS-pipe
//   traffic halved vs the 32x32/2x2 version (which was ~10us LDS-bound).
// Block 512: rank targets by counting (no barriers, validated round 4).
__global__ __launch_bounds__(NT) void supcr_dist_rank(
    const float* __restrict__ E, const float* __restrict__ T,
    float* __restrict__ R, float* __restrict__ tsort, int* __restrict__ inv)
{
    const int bid = blockIdx.x;
    const int t   = threadIdx.x;

    if (bid < 512) {
        __shared__ float4 As4[64 * 9];   // 64 rows x 8 float4, pad to 9
        __shared__ float4 Bs4[64 * 9];   // (row stride 36 dwords: a-reads
        const int tile = bid >> 3, ks = bid & 7;   //  broadcast, b 2-way)
        const int it = tile >> 3, jt = tile & 7;
        const float4* __restrict__ E4 = reinterpret_cast<const float4*>(E);

        #pragma unroll
        for (int p = 0; p < 2; ++p) {            // coalesced staging
            const int idx = t + p * 256;
            const int r = idx >> 3, c4 = idx & 7;
            As4[r * 9 + c4] = E4[(it * 64 + r) * 64 + ks * 8 + c4];
            Bs4[r * 9 + c4] = E4[(jt * 64 + r) * 64 + ks * 8 + c4];
        }
        __syncthreads();

        const int tx = t & 15, ty = t >> 4;      // 16x16 thread grid
        float acc[4][4];
        #pragma unroll
        for (int u = 0; u < 4; ++u)
            #pragma unroll
            for (int v = 0; v < 4; ++v) acc[u][v] = 0.f;

        #pragma unroll
        for (int k4 = 0; k4 < 8; ++k4) {
            float4 a[4], b[4];
            #pragma unroll
            for (int u = 0; u < 4; ++u) a[u] = As4[(ty + 16 * u) * 9 + k4];
            #pragma unroll
            for (int v = 0; v < 4; ++v) b[v] = Bs4[(tx + 16 * v) * 9 + k4];
            #pragma unroll
            for (int u = 0; u < 4; ++u)
                #pragma unroll
                for (int v = 0; v < 4; ++v) ACC4(acc[u][v], a[u], b[v]);
        }

        float* __restrict__ Rp = R + (size_t)ks * RSTRIDE;
        #pragma unroll
        for (int u = 0; u < 4; ++u) {
            const int row = it * 64 + ty + 16 * u;
            #pragma unroll
            for (int v = 0; v < 4; ++v)
                Rp[row * TWO_N + jt * 64 + tx + 16 * v] = acc[u][v];
        }
    } else {
        // rank by counting: stable total order (value, then index)
        __shared__ float Tsh[TWO_N];
        Tsh[t] = T[t]; Tsh[t + 256] = T[t + 256];
        __syncthreads();

        const int ja = t, jb = t + 256;
        const float ta = Tsh[ja], tb = Tsh[jb];
        int rka = 0, rkb = 0;
        const float4* Tsh4 = reinterpret_cast<const float4*>(Tsh);
        #pragma unroll 4
        for (int j4 = 0; j4 < TWO_N / 4; ++j4) {
            const float4 tv = Tsh4[j4];          // LDS broadcast
            const int b0 = 4 * j4, b1 = b0 + 1, b2 = b0 + 2, b3 = b0 + 3;
            rka += (tv.x < ta) || (tv.x == ta && b0 < ja);
            rka += (tv.y < ta) || (tv.y == ta && b1 < ja);
            rka += (tv.z < ta) || (tv.z == ta && b2 < ja);
            rka += (tv.w < ta) || (tv.w == ta && b3 < ja);
            rkb += (tv.x < tb) || (tv.x == tb && b0 < jb);
            rkb += (tv.y < tb) || (tv.y == tb && b1 < jb);
            rkb += (tv.z < tb) || (tv.z == tb && b2 < jb);
            rkb += (tv.w < tb) || (tv.w == tb && b3 < jb);
        }
        tsort[rka] = ta;  inv[ja] = rka;
        tsort[rkb] = tb;  inv[jb] = rkb;
    }
}

// One block per row i, 512 threads (one k each):
//   coalesced partial-sum loads -> rik; LDS scatter via inv; FLOAT shfl
//   scan (validated precision: round-0 float scan passed absmax 0);
//   interval searches; shfl reduce. 5 barriers total.
__global__ __launch_bounds__(NTR) void supcr_rows(
    const float* __restrict__ T, const float* __restrict__ R,
    const float* __restrict__ tsort, const int* __restrict__ inv,
    double* __restrict__ bsums)
{
    const int i = blockIdx.x;
    const int k = threadIdx.x;
    const int lane = k & 63, wid = k >> 6;

    __shared__ float  ts[TWO_N];     // sorted targets
    __shared__ float  Pe[TWO_N];     // s~ scattered into sorted order
    __shared__ float  P[TWO_N];      // inclusive prefix sums
    __shared__ float  wsumf[8];
    __shared__ double red8[8];

    const float ti = T[i];
    const float tk = T[k];

    float d2 = 0.f;
    #pragma unroll
    for (int p = 0; p < KS; ++p)
        d2 += R[(size_t)p * RSTRIDE + (size_t)i * TWO_N + k];
    const float rik = sqrtf(d2);
    const float e   = (k == i) ? 0.f : __expf(-rik);

    ts[k] = tsort[k];
    Pe[inv[k]] = e;                  // scatter: sorted-order s~
    __syncthreads();

    // inclusive scan over sorted order, float, via wave shuffles
    float v = Pe[k];
    #pragma unroll
    for (int off = 1; off < 64; off <<= 1) {
        const float u = __shfl_up(v, off, 64);
        if (lane >= off) v += u;
    }
    if (lane == 63) wsumf[wid] = v;
    __syncthreads();
    float base = 0.f, tot = 0.f;
    #pragma unroll
    for (int w = 0; w < 8; ++w) {
        const float s = wsumf[w];    // LDS broadcast
        tot += s;
        if (w < wid) base += s;
    }
    P[k] = v + base;
    const float Stot = tot;
    __syncthreads();

    const int mi = inv[i];           // scalar load, broadcast

    double local = 0.0;
    if (k != i) {
        const float theta = fabsf(ti - tk);

        // left arm [0, mi]: d(m) = |ti - ts[m]| non-increasing;
        // count leading elements with d >= theta (monotone prefix).
        const int nl = mi + 1;
        int pos = 0;
        #pragma unroll
        for (int step = 512; step >= 1; step >>= 1) {
            const int np = pos + step;
            if (np <= nl && fabsf(ti - ts[np - 1]) >= theta) pos = np;
        }
        const int cl = nl - pos;                 // suffix with d < theta

        // right arm [mi, 511]: d non-decreasing; count leading d < theta.
        const int nr = TWO_N - mi;
        int pr = 0;
        #pragma unroll
        for (int step = 512; step >= 1; step >>= 1) {
            const int np = pr + step;
            if (np <= nr && fabsf(ti - ts[mi + np - 1]) < theta) pr = np;
        }
        const int cr = pr;

        // interval with d < theta: [mi-cl+1, mi+cr-1]
        float inner = 0.f;
        const int L  = mi - cl + 1;
        const int Rr = mi + cr - 1;
        if (Rr >= L) inner = P[Rr] - ((L > 0) ? P[L - 1] : 0.f);
        const float denom = Stot - inner;        // {d >= theta, j != i}
        local = (double)(-rik - logf(denom));
    }

    // block reduction: wave shfl, then 8 partials
    #pragma unroll
    for (int off = 32; off > 0; off >>= 1) local += __shfl_down(local, off, 64);
    if (lane == 0) red8[wid] = local;
    __syncthreads();
    if (k == 0) {
        double s = 0.0;
        #pragma unroll
        for (int w = 0; w < 8; ++w) s += red8[w];
        bsums[i] = s;
    }
}

__global__ __launch_bounds__(64) void supcr_finalize(
    const double* __restrict__ bsums, float* __restrict__ out)
{
    const int t = threadIdx.x;
    double s = 0.0;
    #pragma unroll
    for (int w = 0; w < 8; ++w) s += bsums[t + 64 * w];
    #pragma unroll
    for (int off = 32; off > 0; off >>= 1) s += __shfl_down(s, off, 64);
    if (t == 0)
        out[0] = (float)(-s / (double)((long long)TWO_N * (TWO_N - 1)));
}

extern "C" void kernel_launch(void* const* d_in, const int* in_sizes, int n_in,
                              void* d_out, int out_size, void* d_ws, size_t ws_size,
                              hipStream_t stream) {
    (void)in_sizes; (void)n_in; (void)out_size; (void)ws_size;
    const float* E = (const float*)d_in[0];   // [512,256] fp32
    const float* T = (const float*)d_in[1];   // [512]     fp32
    float* out = (float*)d_out;

    char* ws = (char*)d_ws;
    float*  R      = (float*)(ws);
    float*  tsortp = (float*)(ws + OFF_TSORT);
    int*    invp   = (int*)(ws + OFF_INV);
    double* bsums  = (double*)(ws + OFF_BSUM);

    supcr_dist_rank<<<513, NT, 0, stream>>>(E, T, R, tsortp, invp);
    supcr_rows<<<TWO_N, NTR, 0, stream>>>(T, R, tsortp, invp, bsums);
    supcr_finalize<<<1, 64, 0, stream>>>(bsums, out);
}

// Round 6
// 76.497 us; speedup vs baseline: 1.5399x; 1.2225x over previous
//
#include <hip/hip_runtime.h>
#include <math.h>

#define TWO_N 512
#define DM    256
#define NT    256

// ws layout (bytes):  (identical to the proven 78.8us round-0 layout)
//   R     : [512*512] float  @ 0          (1 MB)
//   tsort : [512] float      @ 1048576
//   perm  : [512] int        @ 1050624
//   inv   : [512] int        @ 1052672
//   bsums : [512] double     @ 1054720
#define OFF_TSORT 1048576
#define OFF_PERM  1050624
#define OFF_INV   1052672
#define OFF_BSUM  1054720

#define ACC4(acc, A, B) { float _d;                      \
    _d = (A).x - (B).x; acc += _d * _d;                  \
    _d = (A).y - (B).y; acc += _d * _d;                  \
    _d = (A).z - (B).z; acc += _d * _d;                  \
    _d = (A).w - (B).w; acc += _d * _d; }

// Blocks 0..255: 32x32 distance tiles (squared-diff "GEMM"), coalesced.
// Block 256: bitonic sort of targets -> tsort/perm/inv.
// (byte-identical to the 78.8us round-0 kernel)
__global__ __launch_bounds__(NT) void supcr_dist_sort(
    const float* __restrict__ E, const float* __restrict__ T,
    float* __restrict__ R, float* __restrict__ tsort,
    int* __restrict__ perm, int* __restrict__ inv)
{
    const int bid = blockIdx.x;
    const int t   = threadIdx.x;

    if (bid < 256) {
        __shared__ float4 As4[32 * 65];
        __shared__ float4 Bs4[32 * 65];
        const int it = bid >> 4, jt = bid & 15;
        const float4* __restrict__ E4 = reinterpret_cast<const float4*>(E);

        for (int idx = t; idx < 32 * 64; idx += NT) {    // coalesced staging
            const int row = idx >> 6, c4 = idx & 63;
            As4[row * 65 + c4] = E4[(it * 32 + row) * 64 + c4];
            Bs4[row * 65 + c4] = E4[(jt * 32 + row) * 64 + c4];
        }
        __syncthreads();

        const int ty = t >> 4, tx = t & 15;
        float a00 = 0.f, a01 = 0.f, a10 = 0.f, a11 = 0.f;
        #pragma unroll 8
        for (int k4 = 0; k4 < 64; ++k4) {
            const float4 a0 = As4[ty * 65 + k4];
            const float4 a1 = As4[(ty + 16) * 65 + k4];
            const float4 b0 = Bs4[tx * 65 + k4];
            const float4 b1 = Bs4[(tx + 16) * 65 + k4];
            ACC4(a00, a0, b0); ACC4(a01, a0, b1);
            ACC4(a10, a1, b0); ACC4(a11, a1, b1);
        }
        const int r0 = it * 32 + ty, r1 = r0 + 16;
        const int c0 = jt * 32 + tx, c1 = c0 + 16;
        R[r0 * TWO_N + c0] = sqrtf(a00);
        R[r0 * TWO_N + c1] = sqrtf(a01);
        R[r1 * TWO_N + c0] = sqrtf(a10);
        R[r1 * TWO_N + c1] = sqrtf(a11);
    } else {
        __shared__ float key[TWO_N];
        __shared__ int   pay[TWO_N];
        key[t] = T[t]; key[t + 256] = T[t + 256];
        pay[t] = t;    pay[t + 256] = t + 256;
        __syncthreads();
        for (int kk = 2; kk <= TWO_N; kk <<= 1) {
            for (int j = kk >> 1; j > 0; j >>= 1) {
                #pragma unroll
                for (int w = 0; w < 2; ++w) {
                    const int e = t + w * 256;
                    const int p = e ^ j;
                    if (p > e) {
                        const float a = key[e], b = key[p];
                        const int  pa = pay[e], pb = pay[p];
                        const bool up = ((e & kk) == 0);
                        if (up ? (a > b) : (a < b)) {
                            key[e] = b; key[p] = a;
                            pay[e] = pb; pay[p] = pa;
                        }
                    }
                }
                __syncthreads();
            }
        }
        tsort[t] = key[t];           tsort[t + 256] = key[t + 256];
        perm[t]  = pay[t];           perm[t + 256]  = pay[t + 256];
        inv[pay[t]] = t;             inv[pay[t + 256]] = t + 256;
    }
}

// One block per row i, 256 threads, 2 sorted slots each (m0=t, m1=t+256).
// vs round-0: (1) Hillis-Steele 18-barrier scan -> 2-barrier wave shfl scan
// computed straight from the gather (no Pe round-trip); (2) the four binary-
// search chains run interleaved in ONE loop (4 independent ds_reads/step).
__global__ __launch_bounds__(NT) void supcr_rows(
    const float* __restrict__ T, const float* __restrict__ R,
    const float* __restrict__ tsort, const int* __restrict__ perm,
    const int* __restrict__ inv, double* __restrict__ bsums)
{
    const int i    = blockIdx.x;
    const int t    = threadIdx.x;
    const int lane = t & 63, wid = t >> 6;       // 4 waves

    __shared__ float  ts[TWO_N];
    __shared__ float  P[TWO_N];      // inclusive prefix sums (sorted order)
    __shared__ float  wsum[8];       // [0..3]=half0 wave totals, [4..7]=half1
    __shared__ double red4[4];

    const float ti = T[i];
    const int m0 = t, m1 = t + 256;

    // ---- stage + gather, values straight to registers ----
    ts[m0] = tsort[m0];  ts[m1] = tsort[m1];
    const int pj0 = perm[m0], pj1 = perm[m1];
    float v0 = (pj0 == i) ? 0.f : __expf(-R[(size_t)i * TWO_N + pj0]);
    float v1 = (pj1 == i) ? 0.f : __expf(-R[(size_t)i * TWO_N + pj1]);

    // ---- wave-level inclusive scan of both halves (interleaved) ----
    #pragma unroll
    for (int off = 1; off < 64; off <<= 1) {
        const float u0 = __shfl_up(v0, off, 64);
        const float u1 = __shfl_up(v1, off, 64);
        if (lane >= off) { v0 += u0; v1 += u1; }
    }
    if (lane == 63) { wsum[wid] = v0; wsum[4 + wid] = v1; }
    __syncthreads();

    float b0 = 0.f, tot = 0.f;
    #pragma unroll
    for (int w = 0; w < 4; ++w) {
        const float s = wsum[w];
        tot += s;
        if (w < wid) b0 += s;
    }
    float b1 = tot;                              // all of half 0
    #pragma unroll
    for (int w = 0; w < 4; ++w) {
        const float s = wsum[4 + w];
        tot += s;
        if (w < wid) b1 += s;
    }
    P[m0] = v0 + b0;
    P[m1] = v1 + b1;
    const float Stot = tot;
    __syncthreads();

    const int mi = inv[i];                       // scalar broadcast
    const int nl = mi + 1;
    const int nr = TWO_N - mi;

    const float theta0 = fabsf(ti - T[m0]);
    const float theta1 = fabsf(ti - T[m1]);
    const float rik0   = R[(size_t)i * TWO_N + m0];
    const float rik1   = R[(size_t)i * TWO_N + m1];

    // ---- 4 binary-search chains interleaved (left/right x item0/item1) ----
    int pos0 = 0, pr0 = 0, pos1 = 0, pr1 = 0;
    #pragma unroll
    for (int step = 512; step >= 1; step >>= 1) {
        const int a0 = pos0 + step, c0 = pr0 + step;
        const int a1 = pos1 + step, c1 = pr1 + step;
        if (a0 <= nl && fabsf(ti - ts[a0 - 1])      >= theta0) pos0 = a0;
        if (c0 <= nr && fabsf(ti - ts[mi + c0 - 1]) <  theta0) pr0  = c0;
        if (a1 <= nl && fabsf(ti - ts[a1 - 1])      >= theta1) pos1 = a1;
        if (c1 <= nr && fabsf(ti - ts[mi + c1 - 1]) <  theta1) pr1  = c1;
    }

    float lf = 0.f;
    if (m0 != i) {
        const int cl = nl - pos0, cr = pr0;      // interval [L, Rr]: d < theta
        const int L = mi - cl + 1, Rr = mi + cr - 1;
        float inner = 0.f;
        if (Rr >= L) inner = P[Rr] - ((L > 0) ? P[L - 1] : 0.f);
        lf += -rik0 - logf(Stot - inner);
    }
    if (m1 != i) {
        const int cl = nl - pos1, cr = pr1;
        const int L = mi - cl + 1, Rr = mi + cr - 1;
        float inner = 0.f;
        if (Rr >= L) inner = P[Rr] - ((L > 0) ? P[L - 1] : 0.f);
        lf += -rik1 - logf(Stot - inner);
    }

    // ---- block reduction: wave shfl + 4 partials ----
    double ld = (double)lf;
    #pragma unroll
    for (int off = 32; off > 0; off >>= 1) ld += __shfl_down(ld, off, 64);
    if (lane == 0) red4[wid] = ld;
    __syncthreads();
    if (t == 0) bsums[i] = red4[0] + red4[1] + red4[2] + red4[3];
}

// byte-identical to round 0
__global__ __launch_bounds__(TWO_N) void supcr_finalize(
    const double* __restrict__ bsums, float* __restrict__ out)
{
    __shared__ double red[TWO_N];
    const int t = threadIdx.x;
    red[t] = bsums[t];
    __syncthreads();
    for (int off = TWO_N / 2; off > 0; off >>= 1) {
        if (t < off) red[t] += red[t + off];
        __syncthreads();
    }
    if (t == 0)
        out[0] = (float)(-red[0] / (double)((long long)TWO_N * (TWO_N - 1)));
}

extern "C" void kernel_launch(void* const* d_in, const int* in_sizes, int n_in,
                              void* d_out, int out_size, void* d_ws, size_t ws_size,
                              hipStream_t stream) {
    (void)in_sizes; (void)n_in; (void)out_size; (void)ws_size;
    const float* E = (const float*)d_in[0];   // [512,256] fp32
    const float* T = (const float*)d_in[1];   // [512]     fp32
    float* out = (float*)d_out;

    char* ws = (char*)d_ws;
    float*  R      = (float*)(ws);
    float*  tsortp = (float*)(ws + OFF_TSORT);
    int*    permp  = (int*)(ws + OFF_PERM);
    int*    invp   = (int*)(ws + OFF_INV);
    double* bsums  = (double*)(ws + OFF_BSUM);

    supcr_dist_sort<<<257, NT, 0, stream>>>(E, T, R, tsortp, permp, invp);
    supcr_rows<<<TWO_N, NT, 0, stream>>>(T, R, tsortp, permp, invp, bsums);
    supcr_finalize<<<1, TWO_N, 0, stream>>>(bsums, out);
}